// Round 4
// baseline (1592.332 us; speedup 1.0000x reference)
//
#include <hip/hip_runtime.h>

#define EMBED 128
#define OUT_EMBED 256
#define NUM_RBF 6
#define N_EDGES_C 640000
#define N_PARTICLES_C 20000

// ---------------------------------------------------------------------------
// Kernel 1: gated = messages * (rbf @ W_rbf); atomic scatter-add into summed
// 8 edges per 256-thread block-iteration; 32 threads/edge, 4 floats/thread.
// ---------------------------------------------------------------------------
__global__ __launch_bounds__(256) void edge_kernel(
    const float* __restrict__ messages,
    const float* __restrict__ rbf,
    const int*   __restrict__ idx_i,
    const float* __restrict__ W_rbf,
    float* __restrict__ summed,
    int n_groups)   // groups of 8 edges
{
    __shared__ float wr[NUM_RBF * EMBED];   // 3 KB
    for (int i = threadIdx.x; i < NUM_RBF * EMBED; i += 256)
        wr[i] = W_rbf[i];
    __syncthreads();

    const int tid = threadIdx.x;
    const int el  = tid >> 5;           // edge within group (0..7)
    const int c4  = (tid & 31) * 4;     // column base (0..124)

    for (int g = blockIdx.x; g < n_groups; g += gridDim.x) {
        const int e = g * 8 + el;
        float r[NUM_RBF];
        #pragma unroll
        for (int k = 0; k < NUM_RBF; ++k) r[k] = rbf[e * NUM_RBF + k];
        const int p = idx_i[e];
        const float4 m = *(const float4*)&messages[e * EMBED + c4];

        float g0 = 0.f, g1 = 0.f, g2 = 0.f, g3 = 0.f;
        #pragma unroll
        for (int k = 0; k < NUM_RBF; ++k) {
            const float4 w = *(const float4*)&wr[k * EMBED + c4];
            g0 = fmaf(r[k], w.x, g0);
            g1 = fmaf(r[k], w.y, g1);
            g2 = fmaf(r[k], w.z, g2);
            g3 = fmaf(r[k], w.w, g3);
        }
        float* dst = summed + (size_t)p * EMBED + c4;
        atomicAdd(dst + 0, m.x * g0);
        atomicAdd(dst + 1, m.y * g1);
        atomicAdd(dst + 2, m.z * g2);
        atomicAdd(dst + 3, m.w * g3);
    }
}

// ---------------------------------------------------------------------------
// Kernel 2: C[M][256] = act(A[M][K] @ W[K][256] (+ bias))
// BM=32 rows/block, full N=256, KT=32. Thread micro-tile 4 rows x 8 cols.
// ---------------------------------------------------------------------------
template<int K, bool BIAS, bool SWISH>
__global__ __launch_bounds__(256) void dense_kernel(
    const float* __restrict__ A,
    const float* __restrict__ W,
    const float* __restrict__ bias,
    float* __restrict__ C,
    int M)
{
    constexpr int BM = 32, BN = 256, KT = 32;
    __shared__ float Ws[KT][BN];        // 32 KB
    __shared__ float As[BM][KT + 1];    // 4.2 KB, padded

    const int tid = threadIdx.x;
    const int tx  = tid & 31;           // cols 8*tx .. 8*tx+7
    const int ty  = tid >> 5;           // rows 4*ty .. 4*ty+3
    const int r0  = blockIdx.x * BM;

    float acc[4][8];
    #pragma unroll
    for (int i = 0; i < 4; ++i)
        #pragma unroll
        for (int j = 0; j < 8; ++j) acc[i][j] = 0.f;

    for (int k0 = 0; k0 < K; k0 += KT) {
        // stage W chunk: KT x 256 floats = 2048 float4
        {
            const float4* Wv  = (const float4*)(W + (size_t)k0 * BN);
            float4* Wsv = (float4*)&Ws[0][0];
            #pragma unroll
            for (int i = 0; i < 8; ++i)
                Wsv[tid + i * 256] = Wv[tid + i * 256];
        }
        // stage A chunk: BM x KT (row-major, padded)
        {
            const int kk = tid & 31;
            const int rr = tid >> 5;       // 0..7
            #pragma unroll
            for (int i = 0; i < 4; ++i) {
                const int r = rr + i * 8;
                As[r][kk] = A[(size_t)(r0 + r) * K + k0 + kk];
            }
        }
        __syncthreads();

        #pragma unroll
        for (int k = 0; k < KT; ++k) {
            float av[4];
            #pragma unroll
            for (int i = 0; i < 4; ++i) av[i] = As[4 * ty + i][k];
            const float4 b0 = *(const float4*)&Ws[k][8 * tx];
            const float4 b1 = *(const float4*)&Ws[k][8 * tx + 4];
            const float bv[8] = {b0.x, b0.y, b0.z, b0.w, b1.x, b1.y, b1.z, b1.w};
            #pragma unroll
            for (int i = 0; i < 4; ++i)
                #pragma unroll
                for (int j = 0; j < 8; ++j)
                    acc[i][j] = fmaf(av[i], bv[j], acc[i][j]);
        }
        __syncthreads();
    }

    #pragma unroll
    for (int i = 0; i < 4; ++i) {
        const int row = r0 + 4 * ty + i;
        float* Crow = C + (size_t)row * BN + 8 * tx;
        #pragma unroll
        for (int j = 0; j < 8; ++j) {
            float v = acc[i][j];
            if (BIAS)  v += bias[8 * tx + j];
            if (SWISH) v = v / (1.f + __expf(-v));
            Crow[j] = v;
        }
    }
}

// ---------------------------------------------------------------------------
// Kernel 3: out[M] = h[M][256] @ W_final[256]
// 32 rows/block; 8 lanes per row; shfl reduce.
// ---------------------------------------------------------------------------
__global__ __launch_bounds__(256) void final_kernel(
    const float* __restrict__ h,
    const float* __restrict__ Wf,
    float* __restrict__ out,
    int M)
{
    const int tid   = threadIdx.x;
    const int rloc  = tid >> 3;      // 0..31
    const int lane8 = tid & 7;
    const int row   = blockIdx.x * 32 + rloc;
    if (row >= M) return;

    const float* hr = h + (size_t)row * OUT_EMBED;
    float acc = 0.f;
    #pragma unroll
    for (int i = 0; i < 8; ++i) {
        const float4 v = *(const float4*)&hr[lane8 * 4 + i * 32];
        const float4 w = *(const float4*)&Wf[lane8 * 4 + i * 32];
        acc += v.x * w.x + v.y * w.y + v.z * w.z + v.w * w.w;
    }
    acc += __shfl_xor(acc, 1);
    acc += __shfl_xor(acc, 2);
    acc += __shfl_xor(acc, 4);
    if (lane8 == 0) out[row] = acc;
}

extern "C" void kernel_launch(void* const* d_in, const int* in_sizes, int n_in,
                              void* d_out, int out_size, void* d_ws, size_t ws_size,
                              hipStream_t stream) {
    const float* messages = (const float*)d_in[0];
    const float* rbf      = (const float*)d_in[1];
    const int*   idx_i    = (const int*)d_in[2];
    // d_in[3] = n_particles scalar (known: 20000)
    const float* W_rbf    = (const float*)d_in[4];
    const float* W_up     = (const float*)d_in[5];
    const float* W_dense  = (const float*)d_in[6];
    const float* b_dense  = (const float*)d_in[7];
    const float* W_final  = (const float*)d_in[8];
    float* out = (float*)d_out;

    float* ws     = (float*)d_ws;
    float* summed = ws;                                  // 20000*128
    float* hA     = ws + (size_t)N_PARTICLES_C * EMBED;  // 20000*256
    float* hB     = hA + (size_t)N_PARTICLES_C * OUT_EMBED;

    hipMemsetAsync(summed, 0, (size_t)N_PARTICLES_C * EMBED * sizeof(float), stream);

    edge_kernel<<<8192, 256, 0, stream>>>(messages, rbf, idx_i, W_rbf, summed,
                                          N_EDGES_C / 8);

    dense_kernel<EMBED, false, false><<<N_PARTICLES_C / 32, 256, 0, stream>>>(
        summed, W_up, nullptr, hA, N_PARTICLES_C);

    dense_kernel<OUT_EMBED, true, true><<<N_PARTICLES_C / 32, 256, 0, stream>>>(
        hA, W_dense + 0 * OUT_EMBED * OUT_EMBED, b_dense + 0 * OUT_EMBED, hB, N_PARTICLES_C);
    dense_kernel<OUT_EMBED, true, true><<<N_PARTICLES_C / 32, 256, 0, stream>>>(
        hB, W_dense + 1 * OUT_EMBED * OUT_EMBED, b_dense + 1 * OUT_EMBED, hA, N_PARTICLES_C);
    dense_kernel<OUT_EMBED, true, true><<<N_PARTICLES_C / 32, 256, 0, stream>>>(
        hA, W_dense + 2 * OUT_EMBED * OUT_EMBED, b_dense + 2 * OUT_EMBED, hB, N_PARTICLES_C);

    final_kernel<<<N_PARTICLES_C / 32, 256, 0, stream>>>(hB, W_final, out, N_PARTICLES_C);
}

// Round 6
// 789.151 us; speedup vs baseline: 2.0178x; 2.0178x over previous
//
#include <hip/hip_runtime.h>

#define EMBED 128
#define OUT_EMBED 256
#define NUM_RBF 6
#define N_EDGES_C 640000
#define N_PARTICLES_C 20000

// ---------------------------------------------------------------------------
// Edge phase, atomic-free main loop: counting-sort edges by particle (CSR),
// then gather-accumulate per particle (1 wave/particle, registers only).
// ---------------------------------------------------------------------------

__global__ __launch_bounds__(256) void hist_kernel(
    const int* __restrict__ idx_i, int* __restrict__ counts)
{
    const int e = blockIdx.x * 256 + threadIdx.x;
    if (e < N_EDGES_C) atomicAdd(&counts[idx_i[e]], 1);
}

// Exclusive scan of counts[20000] -> offsets[20001]; also initializes cursor.
__global__ __launch_bounds__(1024) void scan_kernel(
    const int* __restrict__ counts, int* __restrict__ offsets,
    int* __restrict__ cursor)
{
    __shared__ int sm[1024];
    __shared__ int carry;
    const int tid = threadIdx.x;
    if (tid == 0) carry = 0;
    __syncthreads();
    for (int base = 0; base < N_PARTICLES_C; base += 1024) {
        const int idx = base + tid;
        int v = (idx < N_PARTICLES_C) ? counts[idx] : 0;
        sm[tid] = v;
        __syncthreads();
        for (int off = 1; off < 1024; off <<= 1) {
            int t = (tid >= off) ? sm[tid - off] : 0;
            __syncthreads();
            sm[tid] += t;
            __syncthreads();
        }
        const int excl = carry + sm[tid] - v;   // exclusive prefix
        if (idx < N_PARTICLES_C) { offsets[idx] = excl; cursor[idx] = excl; }
        __syncthreads();                        // all carry reads done
        if (tid == 1023) carry += sm[1023];
        __syncthreads();
    }
    if (tid == 0) offsets[N_PARTICLES_C] = carry;   // = N_EDGES_C
}

__global__ __launch_bounds__(256) void scatter_kernel(
    const int* __restrict__ idx_i, int* __restrict__ cursor,
    int* __restrict__ sorted_eid)
{
    const int e = blockIdx.x * 256 + threadIdx.x;
    if (e < N_EDGES_C) {
        const int p = idx_i[e];
        const int pos = atomicAdd(&cursor[p], 1);
        sorted_eid[pos] = e;
    }
}

// One wave per particle: acc[2]/lane in registers, single write at the end.
__global__ __launch_bounds__(256) void gather_kernel(
    const float* __restrict__ messages,
    const float* __restrict__ rbf,
    const float* __restrict__ W_rbf,
    const int*   __restrict__ offsets,
    const int*   __restrict__ sorted_eid,
    float* __restrict__ summed)
{
    const int wid  = threadIdx.x >> 6;        // wave in block (0..3)
    const int lane = threadIdx.x & 63;
    const int p    = blockIdx.x * 4 + wid;
    const int c2   = lane * 2;                // columns c2, c2+1

    // loop-invariant W_rbf columns -> 12 registers (L2-resident reads)
    float w0[NUM_RBF], w1[NUM_RBF];
    #pragma unroll
    for (int k = 0; k < NUM_RBF; ++k) {
        w0[k] = W_rbf[k * EMBED + c2];
        w1[k] = W_rbf[k * EMBED + c2 + 1];
    }

    const int jb = offsets[p];
    const int je = offsets[p + 1];
    float a0 = 0.f, a1 = 0.f;
    for (int j = jb; j < je; ++j) {
        const int e = sorted_eid[j];                       // wave-uniform
        float r[NUM_RBF];
        #pragma unroll
        for (int k = 0; k < NUM_RBF; ++k) r[k] = rbf[e * NUM_RBF + k];  // broadcast
        const float2 m = *(const float2*)&messages[(size_t)e * EMBED + c2];
        float g0 = 0.f, g1 = 0.f;
        #pragma unroll
        for (int k = 0; k < NUM_RBF; ++k) {
            g0 = fmaf(r[k], w0[k], g0);
            g1 = fmaf(r[k], w1[k], g1);
        }
        a0 = fmaf(m.x, g0, a0);
        a1 = fmaf(m.y, g1, a1);
    }
    *(float2*)&summed[(size_t)p * EMBED + c2] = make_float2(a0, a1);
}

// ---------------------------------------------------------------------------
// Kernel 2: C[M][256] = act(A[M][K] @ W[K][256] (+ bias))  (unchanged)
// ---------------------------------------------------------------------------
template<int K, bool BIAS, bool SWISH>
__global__ __launch_bounds__(256) void dense_kernel(
    const float* __restrict__ A,
    const float* __restrict__ W,
    const float* __restrict__ bias,
    float* __restrict__ C,
    int M)
{
    constexpr int BM = 32, BN = 256, KT = 32;
    __shared__ float Ws[KT][BN];        // 32 KB
    __shared__ float As[BM][KT + 1];    // 4.2 KB, padded

    const int tid = threadIdx.x;
    const int tx  = tid & 31;           // cols 8*tx .. 8*tx+7
    const int ty  = tid >> 5;           // rows 4*ty .. 4*ty+3
    const int r0  = blockIdx.x * BM;

    float acc[4][8];
    #pragma unroll
    for (int i = 0; i < 4; ++i)
        #pragma unroll
        for (int j = 0; j < 8; ++j) acc[i][j] = 0.f;

    for (int k0 = 0; k0 < K; k0 += KT) {
        {
            const float4* Wv  = (const float4*)(W + (size_t)k0 * BN);
            float4* Wsv = (float4*)&Ws[0][0];
            #pragma unroll
            for (int i = 0; i < 8; ++i)
                Wsv[tid + i * 256] = Wv[tid + i * 256];
        }
        {
            const int kk = tid & 31;
            const int rr = tid >> 5;       // 0..7
            #pragma unroll
            for (int i = 0; i < 4; ++i) {
                const int r = rr + i * 8;
                As[r][kk] = A[(size_t)(r0 + r) * K + k0 + kk];
            }
        }
        __syncthreads();

        #pragma unroll
        for (int k = 0; k < KT; ++k) {
            float av[4];
            #pragma unroll
            for (int i = 0; i < 4; ++i) av[i] = As[4 * ty + i][k];
            const float4 b0 = *(const float4*)&Ws[k][8 * tx];
            const float4 b1 = *(const float4*)&Ws[k][8 * tx + 4];
            const float bv[8] = {b0.x, b0.y, b0.z, b0.w, b1.x, b1.y, b1.z, b1.w};
            #pragma unroll
            for (int i = 0; i < 4; ++i)
                #pragma unroll
                for (int j = 0; j < 8; ++j)
                    acc[i][j] = fmaf(av[i], bv[j], acc[i][j]);
        }
        __syncthreads();
    }

    #pragma unroll
    for (int i = 0; i < 4; ++i) {
        const int row = r0 + 4 * ty + i;
        float* Crow = C + (size_t)row * BN + 8 * tx;
        #pragma unroll
        for (int j = 0; j < 8; ++j) {
            float v = acc[i][j];
            if (BIAS)  v += bias[8 * tx + j];
            if (SWISH) v = v / (1.f + __expf(-v));
            Crow[j] = v;
        }
    }
}

// ---------------------------------------------------------------------------
// Kernel 3: out[M] = h[M][256] @ W_final[256]  (unchanged)
// ---------------------------------------------------------------------------
__global__ __launch_bounds__(256) void final_kernel(
    const float* __restrict__ h,
    const float* __restrict__ Wf,
    float* __restrict__ out,
    int M)
{
    const int tid   = threadIdx.x;
    const int rloc  = tid >> 3;      // 0..31
    const int lane8 = tid & 7;
    const int row   = blockIdx.x * 32 + rloc;
    if (row >= M) return;

    const float* hr = h + (size_t)row * OUT_EMBED;
    float acc = 0.f;
    #pragma unroll
    for (int i = 0; i < 8; ++i) {
        const float4 v = *(const float4*)&hr[lane8 * 4 + i * 32];
        const float4 w = *(const float4*)&Wf[lane8 * 4 + i * 32];
        acc += v.x * w.x + v.y * w.y + v.z * w.z + v.w * w.w;
    }
    acc += __shfl_xor(acc, 1);
    acc += __shfl_xor(acc, 2);
    acc += __shfl_xor(acc, 4);
    if (lane8 == 0) out[row] = acc;
}

extern "C" void kernel_launch(void* const* d_in, const int* in_sizes, int n_in,
                              void* d_out, int out_size, void* d_ws, size_t ws_size,
                              hipStream_t stream) {
    const float* messages = (const float*)d_in[0];
    const float* rbf      = (const float*)d_in[1];
    const int*   idx_i    = (const int*)d_in[2];
    // d_in[3] = n_particles scalar (known: 20000)
    const float* W_rbf    = (const float*)d_in[4];
    const float* W_up     = (const float*)d_in[5];
    const float* W_dense  = (const float*)d_in[6];
    const float* b_dense  = (const float*)d_in[7];
    const float* W_final  = (const float*)d_in[8];
    float* out = (float*)d_out;

    float* ws     = (float*)d_ws;
    float* summed = ws;                                  // 20000*128
    float* hA     = ws + (size_t)N_PARTICLES_C * EMBED;  // 20000*256
    float* hB     = hA + (size_t)N_PARTICLES_C * OUT_EMBED;

    // int scratch aliased into hA region (live only during edge phase;
    // dense writes hA strictly after gather_kernel completes).
    int* counts     = (int*)hA;                 // 20000
    int* offsets    = counts + N_PARTICLES_C;   // 20001
    int* cursor     = offsets + N_PARTICLES_C + 1;  // 20000
    int* sorted_eid = cursor + N_PARTICLES_C;   // 640000  (total ~0.7M ints < 5.12M floats)

    hipMemsetAsync(counts, 0, N_PARTICLES_C * sizeof(int), stream);

    hist_kernel<<<N_EDGES_C / 256, 256, 0, stream>>>(idx_i, counts);
    scan_kernel<<<1, 1024, 0, stream>>>(counts, offsets, cursor);
    scatter_kernel<<<N_EDGES_C / 256, 256, 0, stream>>>(idx_i, cursor, sorted_eid);
    gather_kernel<<<N_PARTICLES_C / 4, 256, 0, stream>>>(
        messages, rbf, W_rbf, offsets, sorted_eid, summed);

    dense_kernel<EMBED, false, false><<<N_PARTICLES_C / 32, 256, 0, stream>>>(
        summed, W_up, nullptr, hA, N_PARTICLES_C);

    dense_kernel<OUT_EMBED, true, true><<<N_PARTICLES_C / 32, 256, 0, stream>>>(
        hA, W_dense + 0 * OUT_EMBED * OUT_EMBED, b_dense + 0 * OUT_EMBED, hB, N_PARTICLES_C);
    dense_kernel<OUT_EMBED, true, true><<<N_PARTICLES_C / 32, 256, 0, stream>>>(
        hB, W_dense + 1 * OUT_EMBED * OUT_EMBED, b_dense + 1 * OUT_EMBED, hA, N_PARTICLES_C);
    dense_kernel<OUT_EMBED, true, true><<<N_PARTICLES_C / 32, 256, 0, stream>>>(
        hA, W_dense + 2 * OUT_EMBED * OUT_EMBED, b_dense + 2 * OUT_EMBED, hB, N_PARTICLES_C);

    final_kernel<<<N_PARTICLES_C / 32, 256, 0, stream>>>(hB, W_final, out, N_PARTICLES_C);
}

// Round 10
// 686.403 us; speedup vs baseline: 2.3198x; 1.1497x over previous
//
#include <hip/hip_runtime.h>

#define EMBED 128
#define OUT_EMBED 256
#define NUM_RBF 6
#define N_EDGES_C 640000
#define N_PARTICLES_C 20000

typedef __attribute__((ext_vector_type(8))) short short8;
typedef __attribute__((ext_vector_type(4))) float f32x4;
typedef unsigned int u32;
typedef unsigned short u16;

__device__ __forceinline__ u16 f32_to_bf16(float f) {
    u32 u = __float_as_uint(f);
    u = u + 0x7fff + ((u >> 16) & 1);   // RNE
    return (u16)(u >> 16);
}
__device__ __forceinline__ float bf16_to_f32(u16 h) {
    return __uint_as_float(((u32)h) << 16);
}
__device__ __forceinline__ u32 pack_hilo(float f) {
    u16 hi = f32_to_bf16(f);
    float rem = f - bf16_to_f32(hi);
    u16 lo = f32_to_bf16(rem);
    return ((u32)hi << 16) | lo;
}
__device__ __forceinline__ float unpack_f32(u32 v) {
    return __uint_as_float(v & 0xffff0000u) + __uint_as_float(v << 16);
}

// ---------------------------------------------------------------------------
// Edge phase: counting-sort CSR + gather (atomic-free accumulation).
// ---------------------------------------------------------------------------
__global__ __launch_bounds__(256) void hist_kernel(
    const int* __restrict__ idx_i, int* __restrict__ counts)
{
    const int e = blockIdx.x * 256 + threadIdx.x;
    if (e < N_EDGES_C) atomicAdd(&counts[idx_i[e]], 1);
}

// shfl-based exclusive scan of counts[20000] -> offsets[20001], cursor.
__global__ __launch_bounds__(1024) void scan_kernel(
    const int* __restrict__ counts, int* __restrict__ offsets,
    int* __restrict__ cursor)
{
    __shared__ int wsum[16];
    __shared__ int wpre[17];
    __shared__ int carry;
    const int tid  = threadIdx.x;
    const int lane = tid & 63;
    const int wid  = tid >> 6;
    if (tid == 0) carry = 0;
    __syncthreads();
    for (int base = 0; base < N_PARTICLES_C; base += 1024) {
        const int idx = base + tid;
        int v = (idx < N_PARTICLES_C) ? counts[idx] : 0;
        int x = v;
        #pragma unroll
        for (int off = 1; off < 64; off <<= 1) {
            int t = __shfl_up(x, off);
            if (lane >= off) x += t;
        }
        if (lane == 63) wsum[wid] = x;
        __syncthreads();
        if (tid == 0) {
            int run = 0;
            #pragma unroll
            for (int i = 0; i < 16; ++i) { wpre[i] = run; run += wsum[i]; }
            wpre[16] = run;
        }
        __syncthreads();
        const int excl = carry + wpre[wid] + x - v;
        if (idx < N_PARTICLES_C) { offsets[idx] = excl; cursor[idx] = excl; }
        __syncthreads();
        if (tid == 0) carry += wpre[16];
        __syncthreads();
    }
    if (threadIdx.x == 0) offsets[N_PARTICLES_C] = carry;
}

__global__ __launch_bounds__(256) void scatter_kernel(
    const int* __restrict__ idx_i, int* __restrict__ cursor,
    int* __restrict__ sorted_eid)
{
    const int e = blockIdx.x * 256 + threadIdx.x;
    if (e < N_EDGES_C) {
        const int p = idx_i[e];
        const int pos = atomicAdd(&cursor[p], 1);
        sorted_eid[pos] = e;
    }
}

// One wave per particle; writes packed bf16 hi/lo (u32) accumulators.
__global__ __launch_bounds__(256) void gather_kernel(
    const float* __restrict__ messages,
    const float* __restrict__ rbf,
    const float* __restrict__ W_rbf,
    const int*   __restrict__ offsets,
    const int*   __restrict__ sorted_eid,
    u32* __restrict__ summed_hilo)
{
    const int wid  = threadIdx.x >> 6;
    const int lane = threadIdx.x & 63;
    const int p    = blockIdx.x * 4 + wid;
    const int c2   = lane * 2;

    float w0[NUM_RBF], w1[NUM_RBF];
    #pragma unroll
    for (int k = 0; k < NUM_RBF; ++k) {
        w0[k] = W_rbf[k * EMBED + c2];
        w1[k] = W_rbf[k * EMBED + c2 + 1];
    }

    const int jb = offsets[p];
    const int je = offsets[p + 1];
    float a0 = 0.f, a1 = 0.f;
    for (int j = jb; j < je; ++j) {
        const int e = sorted_eid[j];                       // wave-uniform
        float r[NUM_RBF];
        #pragma unroll
        for (int k = 0; k < NUM_RBF; ++k) r[k] = rbf[e * NUM_RBF + k];
        const float2 m = *(const float2*)&messages[(size_t)e * EMBED + c2];
        float g0 = 0.f, g1 = 0.f;
        #pragma unroll
        for (int k = 0; k < NUM_RBF; ++k) {
            g0 = fmaf(r[k], w0[k], g0);
            g1 = fmaf(r[k], w1[k], g1);
        }
        a0 = fmaf(m.x, g0, a0);
        a1 = fmaf(m.y, g1, a1);
    }
    uint2 out;
    out.x = pack_hilo(a0);
    out.y = pack_hilo(a1);
    *(uint2*)&summed_hilo[(size_t)p * EMBED + c2] = out;
}

// ---------------------------------------------------------------------------
// Weight conversion: f32 [K][N] -> fragment-linear bf16 hi/lo planes.
// frag element e = ((kt*16 + nt)*64 + lane)*8 + j  maps to
//   W[kt*32 + (lane>>4)*8 + j][nt*16 + (lane&15)]
// ---------------------------------------------------------------------------
__global__ __launch_bounds__(256) void convert_weights_kernel(
    const float* __restrict__ W_up,      // 128x256
    const float* __restrict__ W_dense,   // 3x256x256
    u16* __restrict__ w1hi, u16* __restrict__ w1lo,
    u16* __restrict__ wdhi, u16* __restrict__ wdlo)
{
    const int gid = blockIdx.x * 256 + threadIdx.x;   // 0 .. 229375
    if (gid < 32768) {
        const int e = gid;
        const int j = e & 7, lane = (e >> 3) & 63, nt = (e >> 9) & 15, kt = e >> 13;
        const int k = kt * 32 + (lane >> 4) * 8 + j;
        const int n = nt * 16 + (lane & 15);
        const float w = W_up[k * 256 + n];
        const u16 hi = f32_to_bf16(w);
        w1hi[e] = hi;
        w1lo[e] = f32_to_bf16(w - bf16_to_f32(hi));
    } else {
        const int t = gid - 32768;                    // 0 .. 196607
        const int layer = t >> 16;                    // 65536 per layer
        const int e = t & 65535;
        const int j = e & 7, lane = (e >> 3) & 63, nt = (e >> 9) & 15, kt = e >> 13;
        const int k = kt * 32 + (lane >> 4) * 8 + j;
        const int n = nt * 16 + (lane & 15);
        const float w = W_dense[layer * 65536 + k * 256 + n];
        const u16 hi = f32_to_bf16(w);
        wdhi[t] = hi;
        wdlo[t] = f32_to_bf16(w - bf16_to_f32(hi));
    }
}

// ---------------------------------------------------------------------------
// Split-bf16 MFMA dense layer: C[M][256] = act(A[M][K] @ W + bias)
// A, C packed u32 hilo. 4 waves x 16 rows, full N=256 per wave.
// ---------------------------------------------------------------------------
template<int K, bool BIAS, bool SWISH>
__global__ __launch_bounds__(256) void mfma_dense_kernel(
    const u32* __restrict__ A,
    const u16* __restrict__ Whi,
    const u16* __restrict__ Wlo,
    const float* __restrict__ bias,
    u32* __restrict__ C,
    int M)
{
    static_assert(K % 32 == 0, "K must be multiple of 32");
    constexpr int NKT = K / 32;
    __shared__ u32 smem[16384];            // 64 KB: W-stage (32 KB) then C-tile

    const int tid  = threadIdx.x;
    const int wave = tid >> 6;
    const int lane = tid & 63;
    const int m0b  = blockIdx.x * 64;
    const int m0   = m0b + wave * 16;

    int rA = m0 + (lane & 15);
    if (rA > M - 1) rA = M - 1;
    const u32* arow = A + (size_t)rA * K;

    f32x4 acc[16];
    #pragma unroll
    for (int nt = 0; nt < 16; ++nt) acc[nt] = (f32x4){0.f, 0.f, 0.f, 0.f};

    for (int kt = 0; kt < NKT; ++kt) {
        // stage W kt-slice: hi 16 KB + lo 16 KB
        {
            const uint4* shi = (const uint4*)(Whi + kt * 8192);
            const uint4* slo = (const uint4*)(Wlo + kt * 8192);
            uint4* dhi = (uint4*)smem;             // 1024 uint4
            uint4* dlo = (uint4*)(smem + 4096);
            #pragma unroll
            for (int i = 0; i < 4; ++i) {
                dhi[tid + i * 256] = shi[tid + i * 256];
                dlo[tid + i * 256] = slo[tid + i * 256];
            }
        }
        __syncthreads();

        // A fragment: 8 packed u32 -> hi/lo short8
        const u32* ap = arow + kt * 32 + (lane >> 4) * 8;
        uint4 a01 = *(const uint4*)ap;
        uint4 a23 = *(const uint4*)(ap + 4);
        short8 ahi, alo;
        u32 av[8] = {a01.x, a01.y, a01.z, a01.w, a23.x, a23.y, a23.z, a23.w};
        #pragma unroll
        for (int j = 0; j < 8; ++j) {
            ahi[j] = (short)(av[j] >> 16);
            alo[j] = (short)(av[j] & 0xffff);
        }

        const short8* bhiT = (const short8*)smem;
        const short8* bloT = (const short8*)(smem + 4096);
        #pragma unroll
        for (int nt = 0; nt < 16; ++nt) {
            const short8 bhi = bhiT[nt * 64 + lane];
            const short8 blo = bloT[nt * 64 + lane];
            acc[nt] = __builtin_amdgcn_mfma_f32_16x16x32_bf16(ahi, bhi, acc[nt], 0, 0, 0);
            acc[nt] = __builtin_amdgcn_mfma_f32_16x16x32_bf16(alo, bhi, acc[nt], 0, 0, 0);
            acc[nt] = __builtin_amdgcn_mfma_f32_16x16x32_bf16(ahi, blo, acc[nt], 0, 0, 0);
        }
        __syncthreads();
    }

    // epilogue: bias + swish + pack into LDS C-tile, then coalesced store
    #pragma unroll
    for (int nt = 0; nt < 16; ++nt) {
        const int col = nt * 16 + (lane & 15);
        float b = 0.f;
        if (BIAS) b = bias[col];
        #pragma unroll
        for (int r = 0; r < 4; ++r) {
            const int row_l = wave * 16 + (lane >> 4) * 4 + r;
            float v = acc[nt][r];
            if (BIAS)  v += b;
            if (SWISH) v = v / (1.f + __expf(-v));
            smem[row_l * 256 + col] = pack_hilo(v);
        }
    }
    __syncthreads();
    {
        const uint4* csrc = (const uint4*)smem;     // 4096 uint4, 64 per row
        #pragma unroll
        for (int i = 0; i < 16; ++i) {
            const int idx = tid + i * 256;
            const int row = m0b + (idx >> 6);
            if (row < M)
                ((uint4*)(C + (size_t)row * 256))[idx & 63] = csrc[idx];
        }
    }
}

// ---------------------------------------------------------------------------
// Final: out[M] = h[M][256] @ W_final[256]; h packed u32 hilo.
// ---------------------------------------------------------------------------
__global__ __launch_bounds__(256) void final_kernel(
    const u32* __restrict__ h,
    const float* __restrict__ Wf,
    float* __restrict__ out,
    int M)
{
    const int tid   = threadIdx.x;
    const int rloc  = tid >> 3;
    const int lane8 = tid & 7;
    const int row   = blockIdx.x * 32 + rloc;
    if (row >= M) return;

    const u32* hr = h + (size_t)row * OUT_EMBED;
    float acc = 0.f;
    #pragma unroll
    for (int i = 0; i < 8; ++i) {
        const uint4  v = *(const uint4*)&hr[lane8 * 4 + i * 32];
        const float4 w = *(const float4*)&Wf[lane8 * 4 + i * 32];
        acc += unpack_f32(v.x) * w.x + unpack_f32(v.y) * w.y
             + unpack_f32(v.z) * w.z + unpack_f32(v.w) * w.w;
    }
    acc += __shfl_xor(acc, 1);
    acc += __shfl_xor(acc, 2);
    acc += __shfl_xor(acc, 4);
    if (lane8 == 0) out[row] = acc;
}

extern "C" void kernel_launch(void* const* d_in, const int* in_sizes, int n_in,
                              void* d_out, int out_size, void* d_ws, size_t ws_size,
                              hipStream_t stream) {
    const float* messages = (const float*)d_in[0];
    const float* rbf      = (const float*)d_in[1];
    const int*   idx_i    = (const int*)d_in[2];
    const float* W_rbf    = (const float*)d_in[4];
    const float* W_up     = (const float*)d_in[5];
    const float* W_dense  = (const float*)d_in[6];
    const float* b_dense  = (const float*)d_in[7];
    const float* W_final  = (const float*)d_in[8];
    float* out = (float*)d_out;

    // workspace layout (u32 units)
    u32* ws          = (u32*)d_ws;
    u32* summed_hilo = ws;                                    // 20000*128
    u32* hA          = summed_hilo + (size_t)N_PARTICLES_C * EMBED;   // 20000*256
    u32* hB          = hA + (size_t)N_PARTICLES_C * OUT_EMBED;        // 20000*256
    u16* w1hi        = (u16*)(hB + (size_t)N_PARTICLES_C * OUT_EMBED);
    u16* w1lo        = w1hi + 32768;
    u16* wdhi        = w1lo + 32768;
    u16* wdlo        = wdhi + 3 * 65536;
    // int scratch aliased into hA region (dead before dense1 writes hA)
    int* counts      = (int*)hA;
    int* offsets     = counts + N_PARTICLES_C;
    int* cursor      = offsets + N_PARTICLES_C + 1;
    int* sorted_eid  = cursor + N_PARTICLES_C;

    convert_weights_kernel<<<896, 256, 0, stream>>>(W_up, W_dense, w1hi, w1lo, wdhi, wdlo);

    hipMemsetAsync(counts, 0, N_PARTICLES_C * sizeof(int), stream);
    hist_kernel<<<N_EDGES_C / 256, 256, 0, stream>>>(idx_i, counts);
    scan_kernel<<<1, 1024, 0, stream>>>(counts, offsets, cursor);
    scatter_kernel<<<N_EDGES_C / 256, 256, 0, stream>>>(idx_i, cursor, sorted_eid);
    gather_kernel<<<N_PARTICLES_C / 4, 256, 0, stream>>>(
        messages, rbf, W_rbf, offsets, sorted_eid, summed_hilo);

    const int gdense = (N_PARTICLES_C + 63) / 64;
    mfma_dense_kernel<EMBED, false, false><<<gdense, 256, 0, stream>>>(
        summed_hilo, w1hi, w1lo, nullptr, hA, N_PARTICLES_C);
    mfma_dense_kernel<OUT_EMBED, true, true><<<gdense, 256, 0, stream>>>(
        hA, wdhi + 0 * 65536, wdlo + 0 * 65536, b_dense + 0 * OUT_EMBED, hB, N_PARTICLES_C);
    mfma_dense_kernel<OUT_EMBED, true, true><<<gdense, 256, 0, stream>>>(
        hB, wdhi + 1 * 65536, wdlo + 1 * 65536, b_dense + 1 * OUT_EMBED, hA, N_PARTICLES_C);
    mfma_dense_kernel<OUT_EMBED, true, true><<<gdense, 256, 0, stream>>>(
        hA, wdhi + 2 * 65536, wdlo + 2 * 65536, b_dense + 2 * OUT_EMBED, hB, N_PARTICLES_C);

    final_kernel<<<N_PARTICLES_C / 32, 256, 0, stream>>>(hB, W_final, out, N_PARTICLES_C);
}